// Round 7
// baseline (445.111 us; speedup 1.0000x reference)
//
#include <hip/hip_runtime.h>
#include <hip/hip_bf16.h>

typedef __attribute__((ext_vector_type(8))) short short8;
typedef __attribute__((ext_vector_type(4))) float f32x4;

__device__ __forceinline__ unsigned short f2bf(float v) {
    __hip_bfloat16 h = __float2bfloat16(v);   // RNE
    return *reinterpret_cast<unsigned short*>(&h);
}
__device__ __forceinline__ float bf2f(unsigned short u) {
    union { unsigned int i; float f; } x;
    x.i = (unsigned int)u << 16;
    return x.f;
}

constexpr int MAXB = 2048;   // max fine buckets (N/64 = 1563 here)

// ---------------------------------------------------------------------------
// Weight pre-transpose: Wt[(r*H + h)*64 + d] = bf16( r<R ? W[r][d][h]
//                                                        : Wself[d][h] ).
// ---------------------------------------------------------------------------
template<int H>
__global__ __launch_bounds__(256) void transpose_w(
    const float* __restrict__ W, const float* __restrict__ Wself,
    unsigned short* __restrict__ Wt, int R)
{
    int i = blockIdx.x * 256 + threadIdx.x;
    int total = (R + 1) * H * 64;
    if (i >= total) return;
    int d = i & 63;
    int hh = i >> 6;               // r*H + h
    int r = hh / H, h = hh % H;    // H compile-time -> shifts
    float v = (r < R) ? W[((size_t)r * 64 + d) * H + h]
                      : Wself[(size_t)d * H + h];
    Wt[i] = f2bf(v);
}

// ---------------------------------------------------------------------------
// MFMA relation GEMM, one (node-tile, relation) pair per block.
// blockIdx.x = node tile (64 nodes), blockIdx.y = r (r==R -> self-loop,
// fp32+bias to Cself; else bf16 to C[r]). B-fragments direct from
// pre-transposed bf16 weights (L2-resident, coalesced dwordx4).
// ---------------------------------------------------------------------------
template<int H>   // 64 (layer1) or 32 (layer2)
__global__ __launch_bounds__(256) void gemm_rel_mfma(
    const float* __restrict__ A, const unsigned short* __restrict__ Wt,
    const float* __restrict__ bias,
    unsigned short* __restrict__ C, float* __restrict__ Cself,
    int N, int R, int relu)
{
    constexpr int AS = 72;   // 144 B/row = 36 words = 4 mod 32 -> 2-way (free)
    __shared__ unsigned short As[64 * AS];
    const int tid = threadIdx.x;
    const int n0 = blockIdx.x * 64;
    const int r = blockIdx.y;

    // Stage A tile fp32 -> bf16 (optional ReLU).
    #pragma unroll
    for (int i = 0; i < 4; ++i) {
        int lin = tid + i * 256;            // 1024 float4 slots
        int n = lin >> 4;
        int d4 = (lin & 15) * 4;
        int gn = n0 + n;
        float4 v = make_float4(0.f, 0.f, 0.f, 0.f);
        if (gn < N) v = *(const float4*)&A[(size_t)gn * 64 + d4];
        if (relu) {
            v.x = fmaxf(v.x, 0.f); v.y = fmaxf(v.y, 0.f);
            v.z = fmaxf(v.z, 0.f); v.w = fmaxf(v.w, 0.f);
        }
        ushort4 u;
        u.x = f2bf(v.x); u.y = f2bf(v.y); u.z = f2bf(v.z); u.w = f2bf(v.w);
        *(ushort4*)&As[n * AS + d4] = u;
    }

    const int w = tid >> 6, lane = tid & 63;
    const int m = lane & 15, quad = lane >> 4;

    __syncthreads();   // the only barrier

    short8 afrag[2];
    afrag[0] = *(const short8*)&As[(w * 16 + m) * AS + 0 * 32 + quad * 8];
    afrag[1] = *(const short8*)&As[(w * 16 + m) * AS + 1 * 32 + quad * 8];

    constexpr int NT = H / 16;
    f32x4 acc[NT];
    #pragma unroll
    for (int nt = 0; nt < NT; ++nt) {
        acc[nt] = (f32x4){0.f, 0.f, 0.f, 0.f};
        #pragma unroll
        for (int kc = 0; kc < 2; ++kc) {
            short8 bfrag = *(const short8*)
                &Wt[((size_t)(r * H + nt * 16 + m)) * 64 + kc * 32 + quad * 8];
            acc[nt] = __builtin_amdgcn_mfma_f32_16x16x32_bf16(afrag[kc], bfrag, acc[nt], 0, 0, 0);
        }
    }
    // C/D layout: col = lane&15 (+nt*16), row = quad*4 + i.
    if (r < R) {
        #pragma unroll
        for (int nt = 0; nt < NT; ++nt) {
            int col = nt * 16 + m;
            #pragma unroll
            for (int i = 0; i < 4; ++i) {
                int node = n0 + w * 16 + quad * 4 + i;
                if (node < N)
                    C[((size_t)r * N + node) * H + col] = f2bf(acc[nt][i]);
            }
        }
    } else {
        #pragma unroll
        for (int nt = 0; nt < NT; ++nt) {
            int col = nt * 16 + m;
            float bv = bias[col];
            #pragma unroll
            for (int i = 0; i < 4; ++i) {
                int node = n0 + w * 16 + quad * 4 + i;
                if (node < N)
                    Cself[(size_t)node * H + col] = acc[nt][i] + bv;
            }
        }
    }
}

// ---------------------------------------------------------------------------
// Bucket partition. Bucket = 64 consecutive dst nodes.
// Record: (et*N + src) << 6 | (dst & 63).
// ---------------------------------------------------------------------------
__global__ __launch_bounds__(256) void zero_int(int* __restrict__ p, int n) {
    int i = blockIdx.x * 256 + threadIdx.x;
    if (i < n) p[i] = 0;
}

__global__ __launch_bounds__(256) void fine_hist(
    const int* __restrict__ dst, int* __restrict__ ghist, int E, int B, int CH)
{
    __shared__ int hist[MAXB];
    const int t = threadIdx.x;
    const int e0 = blockIdx.x * CH, e1 = min(E, e0 + CH);
    for (int i = t; i < B; i += 256) hist[i] = 0;
    __syncthreads();
    for (int e = e0 + t; e < e1; e += 256) atomicAdd(&hist[dst[e] >> 6], 1);
    __syncthreads();
    for (int i = t; i < B; i += 256) {
        int h = hist[i];
        if (h) atomicAdd(&ghist[i], h);
    }
}

__global__ __launch_bounds__(256) void fine_scan(
    const int* __restrict__ ghist, int* __restrict__ bstart,
    int* __restrict__ cursor, int B, int E)
{
    __shared__ int ts[256];
    const int t = threadIdx.x;
    const int PER = (B + 255) / 256;   // <= 8
    int loc[8];
    int s = 0;
    for (int j = 0; j < PER; ++j) {
        int i = t * PER + j;
        loc[j] = (i < B) ? ghist[i] : 0;
        s += loc[j];
    }
    ts[t] = s;
    __syncthreads();
    for (int off = 1; off < 256; off <<= 1) {
        int x = (t >= off) ? ts[t - off] : 0;
        __syncthreads();
        ts[t] += x;
        __syncthreads();
    }
    int run = ts[t] - s;
    for (int j = 0; j < PER; ++j) {
        int i = t * PER + j;
        if (i < B) { bstart[i] = run; cursor[i] = run; }
        run += loc[j];
    }
    if (t == 255) bstart[B] = E;
}

__global__ __launch_bounds__(256) void partition_fine(
    const int* __restrict__ src, const int* __restrict__ dst,
    const int* __restrict__ et, int* __restrict__ cursor,
    int* __restrict__ rec, int E, int N, int B, int CH)
{
    __shared__ int hist[MAXB];
    __shared__ int base[MAXB];
    __shared__ int cnt[MAXB];
    const int t = threadIdx.x;
    const int e0 = blockIdx.x * CH, e1 = min(E, e0 + CH);

    for (int i = t; i < B; i += 256) hist[i] = 0;
    __syncthreads();
    for (int e = e0 + t; e < e1; e += 256) atomicAdd(&hist[dst[e] >> 6], 1);
    __syncthreads();
    for (int i = t; i < B; i += 256) {
        int h = hist[i];
        base[i] = h ? atomicAdd(&cursor[i], h) : 0;
        cnt[i] = 0;
    }
    __syncthreads();
    for (int e = e0 + t; e < e1; e += 256) {
        int d = dst[e];
        int b = d >> 6;
        int pos = base[b] + atomicAdd(&cnt[b], 1);
        rec[pos] = ((et[e] * N + src[e]) << 6) | (d & 63);
    }
}

// ---------------------------------------------------------------------------
// Per-bucket counting sort -> per-node CSR (row_ptr + eidx).
// ---------------------------------------------------------------------------
__global__ __launch_bounds__(256) void bucket_sort(
    const int* __restrict__ bstart, const int* __restrict__ rec,
    int* __restrict__ eidx, int* __restrict__ row_ptr, int N, int E)
{
    __shared__ int hist[64];
    __shared__ int excl[64];
    __shared__ int cur[64];
    const int b = blockIdx.x;
    const int tid = threadIdx.x;
    const int p0 = bstart[b], p1 = bstart[b + 1];

    if (tid < 64) hist[tid] = 0;
    __syncthreads();
    for (int p = p0 + tid; p < p1; p += 256)
        atomicAdd(&hist[rec[p] & 63], 1);
    __syncthreads();
    if (tid == 0) {
        int run = 0;
        #pragma unroll
        for (int i = 0; i < 64; ++i) { excl[i] = run; run += hist[i]; }
    }
    __syncthreads();
    if (tid < 64) {
        cur[tid] = excl[tid];
        int n = b * 64 + tid;
        if (n < N) row_ptr[n] = p0 + excl[tid];
    }
    if (b == 0 && tid == 0) row_ptr[N] = E;
    __syncthreads();
    for (int p = p0 + tid; p < p1; p += 256) {
        int rv = rec[p];
        int pos = p0 + atomicAdd(&cur[rv & 63], 1);
        eidx[pos] = rv >> 6;   // et*N + src
    }
}

// ---------------------------------------------------------------------------
// Gather-side aggregation over bf16 hW, fp32 register accumulate, 4-wide
// unroll with 2 accumulators for memory-level parallelism.
// ---------------------------------------------------------------------------
template<int F>
__global__ __launch_bounds__(256) void agg_csr(
    const unsigned short* __restrict__ hW, const int* __restrict__ row_ptr,
    const int* __restrict__ eidx, float* __restrict__ out, int N)
{
    constexpr int G = 256 / F;
    const int d = blockIdx.x * G + threadIdx.x / F;
    const int lane = threadIdx.x % F;
    if (d >= N) return;
    const int p1 = row_ptr[d + 1];
    int p = row_ptr[d];
    float a0 = 0.f, a1 = 0.f;
    for (; p + 3 < p1; p += 4) {
        int i0 = eidx[p], i1 = eidx[p + 1], i2 = eidx[p + 2], i3 = eidx[p + 3];
        a0 += bf2f(hW[(size_t)i0 * F + lane]);
        a1 += bf2f(hW[(size_t)i1 * F + lane]);
        a0 += bf2f(hW[(size_t)i2 * F + lane]);
        a1 += bf2f(hW[(size_t)i3 * F + lane]);
    }
    for (; p < p1; ++p)
        a0 += bf2f(hW[(size_t)eidx[p] * F + lane]);
    out[(size_t)d * F + lane] += a0 + a1;
}

extern "C" void kernel_launch(void* const* d_in, const int* in_sizes, int n_in,
                              void* d_out, int out_size, void* d_ws, size_t ws_size,
                              hipStream_t stream)
{
    const float* feat = (const float*)d_in[0];
    const int*   src  = (const int*)d_in[1];
    const int*   dst  = (const int*)d_in[2];
    const int*   et   = (const int*)d_in[3];
    const float* W1   = (const float*)d_in[4];
    const float* Ws1  = (const float*)d_in[5];
    const float* b1   = (const float*)d_in[6];
    const float* W2   = (const float*)d_in[7];
    const float* Ws2  = (const float*)d_in[8];
    const float* b2   = (const float*)d_in[9];
    float* out = (float*)d_out;

    const int N = in_sizes[0] / 64;           // 100000
    const int E = in_sizes[1];                // 1600000
    const int R = in_sizes[4] / (64 * 64);    // 8
    const int B = (N + 63) / 64;              // 1563 fine buckets

    // Workspace layout
    unsigned short* hW  = (unsigned short*)d_ws;           // [R][N][64] bf16 (reused [R][N][32])
    float* h1      = (float*)(hW + (size_t)R * N * 64);    // [N][64] fp32
    unsigned short* Wt1 = (unsigned short*)(h1 + (size_t)N * 64);  // [(R+1)*64*64]
    unsigned short* Wt2 = Wt1 + (size_t)(R + 1) * 64 * 64;         // [(R+1)*32*64]
    int*   ghist   = (int*)(Wt2 + (size_t)(R + 1) * 32 * 64);      // [B]
    int*   bstart  = ghist + B;                            // [B+1]
    int*   cursor  = bstart + (B + 1);                     // [B]
    int*   row_ptr = cursor + B;                           // [N+1]
    int*   rec     = row_ptr + (N + 1);                    // [E]
    int*   eidx    = rec + E;                              // [E]

    const dim3 blk(256);
    const int nblk64 = (N + 63) / 64;
    const int P  = 128;                       // partition blocks
    const int CH = (E + P - 1) / P;           // 12500 edges per block

    // ---- Weight pre-transpose (bf16, [r][h][d]) ----
    transpose_w<64><<<((R + 1) * 64 * 64 + 255) / 256, blk, 0, stream>>>(W1, Ws1, Wt1, R);
    transpose_w<32><<<((R + 1) * 32 * 64 + 255) / 256, blk, 0, stream>>>(W2, Ws2, Wt2, R);

    // ---- Build per-node CSR via bucket partition + per-bucket sort ----
    zero_int<<<(B + 255) / 256, blk, 0, stream>>>(ghist, B);
    fine_hist<<<P, blk, 0, stream>>>(dst, ghist, E, B, CH);
    fine_scan<<<1, blk, 0, stream>>>(ghist, bstart, cursor, B, E);
    partition_fine<<<P, blk, 0, stream>>>(src, dst, et, cursor, rec, E, N, B, CH);
    bucket_sort<<<B, blk, 0, stream>>>(bstart, rec, eidx, row_ptr, N, E);

    // ---- Layer 1 ---- (hW1 bf16 + self-loop fp32 into h1, fused; grid y = r)
    gemm_rel_mfma<64><<<dim3(nblk64, R + 1), blk, 0, stream>>>(feat, Wt1, b1, hW, h1, N, R, 0);
    agg_csr<64><<<dim3((N + 3) / 4), blk, 0, stream>>>(hW, row_ptr, eidx, h1, N);

    // ---- Layer 2 ---- (ReLU fused into A staging)
    gemm_rel_mfma<32><<<dim3(nblk64, R + 1), blk, 0, stream>>>(h1, Wt2, b2, hW, out, N, R, 1);
    agg_csr<32><<<dim3((N + 7) / 8), blk, 0, stream>>>(hW, row_ptr, eidx, out, N);
}

// Round 8
// 429.326 us; speedup vs baseline: 1.0368x; 1.0368x over previous
//
#include <hip/hip_runtime.h>
#include <hip/hip_bf16.h>

typedef __attribute__((ext_vector_type(8))) short short8;
typedef __attribute__((ext_vector_type(4))) float f32x4;

__device__ __forceinline__ unsigned short f2bf(float v) {
    __hip_bfloat16 h = __float2bfloat16(v);   // RNE
    return *reinterpret_cast<unsigned short*>(&h);
}
__device__ __forceinline__ float bf2f(unsigned short u) {
    union { unsigned int i; float f; } x;
    x.i = (unsigned int)u << 16;
    return x.f;
}

constexpr int MAXB = 2048;   // max fine buckets (N/64 = 1563 here)

// ---------------------------------------------------------------------------
// Weight pre-transpose: Wt[(r*H + h)*64 + d] = bf16( r<R ? W[r][d][h]
//                                                        : Wself[d][h] ).
// ---------------------------------------------------------------------------
template<int H>
__global__ __launch_bounds__(256) void transpose_w(
    const float* __restrict__ W, const float* __restrict__ Wself,
    unsigned short* __restrict__ Wt, int R)
{
    int i = blockIdx.x * 256 + threadIdx.x;
    int total = (R + 1) * H * 64;
    if (i >= total) return;
    int d = i & 63;
    int hh = i >> 6;               // r*H + h
    int r = hh / H, h = hh % H;    // H compile-time -> shifts
    float v = (r < R) ? W[((size_t)r * 64 + d) * H + h]
                      : Wself[(size_t)d * H + h];
    Wt[i] = f2bf(v);
}

// ---------------------------------------------------------------------------
// MFMA relation GEMM, one (relation, node-tile) pair per block.
// blockIdx.x = r (FAST dispatch dim -> the 9 blocks sharing one A-tile are
// temporally adjacent, so 8 of the 9 A-tile reads hit L2/L3, not HBM).
// blockIdx.y = node tile. r==R -> self-loop, fp32+bias to Cself.
// ---------------------------------------------------------------------------
template<int H>   // 64 (layer1) or 32 (layer2)
__global__ __launch_bounds__(256) void gemm_rel_mfma(
    const float* __restrict__ A, const unsigned short* __restrict__ Wt,
    const float* __restrict__ bias,
    unsigned short* __restrict__ C, float* __restrict__ Cself,
    int N, int R, int relu)
{
    constexpr int AS = 72;   // 144 B/row = 36 words = 4 mod 32 -> 2-way (free)
    __shared__ unsigned short As[64 * AS];
    const int tid = threadIdx.x;
    const int r = blockIdx.x;
    const int n0 = blockIdx.y * 64;

    // Stage A tile fp32 -> bf16 (optional ReLU).
    #pragma unroll
    for (int i = 0; i < 4; ++i) {
        int lin = tid + i * 256;            // 1024 float4 slots
        int n = lin >> 4;
        int d4 = (lin & 15) * 4;
        int gn = n0 + n;
        float4 v = make_float4(0.f, 0.f, 0.f, 0.f);
        if (gn < N) v = *(const float4*)&A[(size_t)gn * 64 + d4];
        if (relu) {
            v.x = fmaxf(v.x, 0.f); v.y = fmaxf(v.y, 0.f);
            v.z = fmaxf(v.z, 0.f); v.w = fmaxf(v.w, 0.f);
        }
        ushort4 u;
        u.x = f2bf(v.x); u.y = f2bf(v.y); u.z = f2bf(v.z); u.w = f2bf(v.w);
        *(ushort4*)&As[n * AS + d4] = u;
    }

    const int w = tid >> 6, lane = tid & 63;
    const int m = lane & 15, quad = lane >> 4;

    __syncthreads();   // the only barrier

    short8 afrag[2];
    afrag[0] = *(const short8*)&As[(w * 16 + m) * AS + 0 * 32 + quad * 8];
    afrag[1] = *(const short8*)&As[(w * 16 + m) * AS + 1 * 32 + quad * 8];

    constexpr int NT = H / 16;
    f32x4 acc[NT];
    #pragma unroll
    for (int nt = 0; nt < NT; ++nt) {
        acc[nt] = (f32x4){0.f, 0.f, 0.f, 0.f};
        #pragma unroll
        for (int kc = 0; kc < 2; ++kc) {
            short8 bfrag = *(const short8*)
                &Wt[((size_t)(r * H + nt * 16 + m)) * 64 + kc * 32 + quad * 8];
            acc[nt] = __builtin_amdgcn_mfma_f32_16x16x32_bf16(afrag[kc], bfrag, acc[nt], 0, 0, 0);
        }
    }
    // C/D layout: col = lane&15 (+nt*16), row = quad*4 + i.
    if (r < R) {
        #pragma unroll
        for (int nt = 0; nt < NT; ++nt) {
            int col = nt * 16 + m;
            #pragma unroll
            for (int i = 0; i < 4; ++i) {
                int node = n0 + w * 16 + quad * 4 + i;
                if (node < N)
                    C[((size_t)r * N + node) * H + col] = f2bf(acc[nt][i]);
            }
        }
    } else {
        #pragma unroll
        for (int nt = 0; nt < NT; ++nt) {
            int col = nt * 16 + m;
            float bv = bias[col];
            #pragma unroll
            for (int i = 0; i < 4; ++i) {
                int node = n0 + w * 16 + quad * 4 + i;
                if (node < N)
                    Cself[(size_t)node * H + col] = acc[nt][i] + bv;
            }
        }
    }
}

// ---------------------------------------------------------------------------
// Bucket partition. Bucket = 64 consecutive dst nodes.
// Record: (et*N + src) << 6 | (dst & 63).
// ---------------------------------------------------------------------------
__global__ __launch_bounds__(256) void zero_int(int* __restrict__ p, int n) {
    int i = blockIdx.x * 256 + threadIdx.x;
    if (i < n) p[i] = 0;
}

__global__ __launch_bounds__(256) void fine_hist(
    const int* __restrict__ dst, int* __restrict__ ghist, int E, int B, int CH)
{
    __shared__ int hist[MAXB];
    const int t = threadIdx.x;
    const int e0 = blockIdx.x * CH, e1 = min(E, e0 + CH);
    for (int i = t; i < B; i += 256) hist[i] = 0;
    __syncthreads();
    for (int e = e0 + t; e < e1; e += 256) atomicAdd(&hist[dst[e] >> 6], 1);
    __syncthreads();
    for (int i = t; i < B; i += 256) {
        int h = hist[i];
        if (h) atomicAdd(&ghist[i], h);
    }
}

__global__ __launch_bounds__(256) void fine_scan(
    const int* __restrict__ ghist, int* __restrict__ bstart,
    int* __restrict__ cursor, int B, int E)
{
    __shared__ int ts[256];
    const int t = threadIdx.x;
    const int PER = (B + 255) / 256;   // <= 8
    int loc[8];
    int s = 0;
    for (int j = 0; j < PER; ++j) {
        int i = t * PER + j;
        loc[j] = (i < B) ? ghist[i] : 0;
        s += loc[j];
    }
    ts[t] = s;
    __syncthreads();
    for (int off = 1; off < 256; off <<= 1) {
        int x = (t >= off) ? ts[t - off] : 0;
        __syncthreads();
        ts[t] += x;
        __syncthreads();
    }
    int run = ts[t] - s;
    for (int j = 0; j < PER; ++j) {
        int i = t * PER + j;
        if (i < B) { bstart[i] = run; cursor[i] = run; }
        run += loc[j];
    }
    if (t == 255) bstart[B] = E;
}

__global__ __launch_bounds__(256) void partition_fine(
    const int* __restrict__ src, const int* __restrict__ dst,
    const int* __restrict__ et, int* __restrict__ cursor,
    int* __restrict__ rec, int E, int N, int B, int CH)
{
    __shared__ int hist[MAXB];
    __shared__ int base[MAXB];
    __shared__ int cnt[MAXB];
    const int t = threadIdx.x;
    const int e0 = blockIdx.x * CH, e1 = min(E, e0 + CH);

    for (int i = t; i < B; i += 256) hist[i] = 0;
    __syncthreads();
    for (int e = e0 + t; e < e1; e += 256) atomicAdd(&hist[dst[e] >> 6], 1);
    __syncthreads();
    for (int i = t; i < B; i += 256) {
        int h = hist[i];
        base[i] = h ? atomicAdd(&cursor[i], h) : 0;
        cnt[i] = 0;
    }
    __syncthreads();
    for (int e = e0 + t; e < e1; e += 256) {
        int d = dst[e];
        int b = d >> 6;
        int pos = base[b] + atomicAdd(&cnt[b], 1);
        rec[pos] = ((et[e] * N + src[e]) << 6) | (d & 63);
    }
}

// ---------------------------------------------------------------------------
// Per-bucket counting sort -> per-node CSR (row_ptr + eidx).
// ---------------------------------------------------------------------------
__global__ __launch_bounds__(256) void bucket_sort(
    const int* __restrict__ bstart, const int* __restrict__ rec,
    int* __restrict__ eidx, int* __restrict__ row_ptr, int N, int E)
{
    __shared__ int hist[64];
    __shared__ int excl[64];
    __shared__ int cur[64];
    const int b = blockIdx.x;
    const int tid = threadIdx.x;
    const int p0 = bstart[b], p1 = bstart[b + 1];

    if (tid < 64) hist[tid] = 0;
    __syncthreads();
    for (int p = p0 + tid; p < p1; p += 256)
        atomicAdd(&hist[rec[p] & 63], 1);
    __syncthreads();
    if (tid == 0) {
        int run = 0;
        #pragma unroll
        for (int i = 0; i < 64; ++i) { excl[i] = run; run += hist[i]; }
    }
    __syncthreads();
    if (tid < 64) {
        cur[tid] = excl[tid];
        int n = b * 64 + tid;
        if (n < N) row_ptr[n] = p0 + excl[tid];
    }
    if (b == 0 && tid == 0) row_ptr[N] = E;
    __syncthreads();
    for (int p = p0 + tid; p < p1; p += 256) {
        int rv = rec[p];
        int pos = p0 + atomicAdd(&cur[rv & 63], 1);
        eidx[pos] = rv >> 6;   // et*N + src
    }
}

// ---------------------------------------------------------------------------
// Gather-side aggregation over bf16 hW, fp32 register accumulate, 8-wide
// unroll with 4 accumulators for memory-level parallelism.
// ---------------------------------------------------------------------------
template<int F>
__global__ __launch_bounds__(256) void agg_csr(
    const unsigned short* __restrict__ hW, const int* __restrict__ row_ptr,
    const int* __restrict__ eidx, float* __restrict__ out, int N)
{
    constexpr int G = 256 / F;
    const int d = blockIdx.x * G + threadIdx.x / F;
    const int lane = threadIdx.x % F;
    if (d >= N) return;
    const int p1 = row_ptr[d + 1];
    int p = row_ptr[d];
    float a0 = 0.f, a1 = 0.f, a2 = 0.f, a3 = 0.f;
    for (; p + 7 < p1; p += 8) {
        int i0 = eidx[p],     i1 = eidx[p + 1], i2 = eidx[p + 2], i3 = eidx[p + 3];
        int i4 = eidx[p + 4], i5 = eidx[p + 5], i6 = eidx[p + 6], i7 = eidx[p + 7];
        a0 += bf2f(hW[(size_t)i0 * F + lane]);
        a1 += bf2f(hW[(size_t)i1 * F + lane]);
        a2 += bf2f(hW[(size_t)i2 * F + lane]);
        a3 += bf2f(hW[(size_t)i3 * F + lane]);
        a0 += bf2f(hW[(size_t)i4 * F + lane]);
        a1 += bf2f(hW[(size_t)i5 * F + lane]);
        a2 += bf2f(hW[(size_t)i6 * F + lane]);
        a3 += bf2f(hW[(size_t)i7 * F + lane]);
    }
    for (; p + 1 < p1; p += 2) {
        int i0 = eidx[p], i1 = eidx[p + 1];
        a0 += bf2f(hW[(size_t)i0 * F + lane]);
        a1 += bf2f(hW[(size_t)i1 * F + lane]);
    }
    if (p < p1) a0 += bf2f(hW[(size_t)eidx[p] * F + lane]);
    out[(size_t)d * F + lane] += (a0 + a1) + (a2 + a3);
}

extern "C" void kernel_launch(void* const* d_in, const int* in_sizes, int n_in,
                              void* d_out, int out_size, void* d_ws, size_t ws_size,
                              hipStream_t stream)
{
    const float* feat = (const float*)d_in[0];
    const int*   src  = (const int*)d_in[1];
    const int*   dst  = (const int*)d_in[2];
    const int*   et   = (const int*)d_in[3];
    const float* W1   = (const float*)d_in[4];
    const float* Ws1  = (const float*)d_in[5];
    const float* b1   = (const float*)d_in[6];
    const float* W2   = (const float*)d_in[7];
    const float* Ws2  = (const float*)d_in[8];
    const float* b2   = (const float*)d_in[9];
    float* out = (float*)d_out;

    const int N = in_sizes[0] / 64;           // 100000
    const int E = in_sizes[1];                // 1600000
    const int R = in_sizes[4] / (64 * 64);    // 8
    const int B = (N + 63) / 64;              // 1563 fine buckets

    // Workspace layout
    unsigned short* hW  = (unsigned short*)d_ws;           // [R][N][64] bf16 (reused [R][N][32])
    float* h1      = (float*)(hW + (size_t)R * N * 64);    // [N][64] fp32
    unsigned short* Wt1 = (unsigned short*)(h1 + (size_t)N * 64);  // [(R+1)*64*64]
    unsigned short* Wt2 = Wt1 + (size_t)(R + 1) * 64 * 64;         // [(R+1)*32*64]
    int*   ghist   = (int*)(Wt2 + (size_t)(R + 1) * 32 * 64);      // [B]
    int*   bstart  = ghist + B;                            // [B+1]
    int*   cursor  = bstart + (B + 1);                     // [B]
    int*   row_ptr = cursor + B;                           // [N+1]
    int*   rec     = row_ptr + (N + 1);                    // [E]
    int*   eidx    = rec + E;                              // [E]

    const dim3 blk(256);
    const int nblk64 = (N + 63) / 64;
    const int P  = 128;                       // partition blocks
    const int CH = (E + P - 1) / P;           // 12500 edges per block

    // ---- Weight pre-transpose (bf16, [r][h][d]) ----
    transpose_w<64><<<((R + 1) * 64 * 64 + 255) / 256, blk, 0, stream>>>(W1, Ws1, Wt1, R);
    transpose_w<32><<<((R + 1) * 32 * 64 + 255) / 256, blk, 0, stream>>>(W2, Ws2, Wt2, R);

    // ---- Build per-node CSR via bucket partition + per-bucket sort ----
    zero_int<<<(B + 255) / 256, blk, 0, stream>>>(ghist, B);
    fine_hist<<<P, blk, 0, stream>>>(dst, ghist, E, B, CH);
    fine_scan<<<1, blk, 0, stream>>>(ghist, bstart, cursor, B, E);
    partition_fine<<<P, blk, 0, stream>>>(src, dst, et, cursor, rec, E, N, B, CH);
    bucket_sort<<<B, blk, 0, stream>>>(bstart, rec, eidx, row_ptr, N, E);

    // ---- Layer 1 ---- (hW1 bf16 + self-loop fp32 into h1, fused; grid x = r)
    gemm_rel_mfma<64><<<dim3(R + 1, nblk64), blk, 0, stream>>>(feat, Wt1, b1, hW, h1, N, R, 0);
    agg_csr<64><<<dim3((N + 3) / 4), blk, 0, stream>>>(hW, row_ptr, eidx, h1, N);

    // ---- Layer 2 ---- (ReLU fused into A staging)
    gemm_rel_mfma<32><<<dim3(R + 1, nblk64), blk, 0, stream>>>(h1, Wt2, b2, hW, out, N, R, 1);
    agg_csr<32><<<dim3((N + 7) / 8), blk, 0, stream>>>(hW, row_ptr, eidx, out, N);
}

// Round 9
// 398.907 us; speedup vs baseline: 1.1158x; 1.0763x over previous
//
#include <hip/hip_runtime.h>
#include <hip/hip_bf16.h>

typedef __attribute__((ext_vector_type(8))) short short8;
typedef __attribute__((ext_vector_type(4))) float f32x4;

__device__ __forceinline__ unsigned short f2bf(float v) {
    __hip_bfloat16 h = __float2bfloat16(v);   // RNE
    return *reinterpret_cast<unsigned short*>(&h);
}
__device__ __forceinline__ float bf2f(unsigned short u) {
    union { unsigned int i; float f; } x;
    x.i = (unsigned int)u << 16;
    return x.f;
}

constexpr int MAXB = 2048;   // max fine buckets (N/64 = 1563 here)

// ---------------------------------------------------------------------------
// Weight pre-transpose: Wt[(r*H + h)*64 + d] = bf16( r<R ? W[r][d][h]
//                                                        : Wself[d][h] ).
// ---------------------------------------------------------------------------
template<int H>
__global__ __launch_bounds__(256) void transpose_w(
    const float* __restrict__ W, const float* __restrict__ Wself,
    unsigned short* __restrict__ Wt, int R)
{
    int i = blockIdx.x * 256 + threadIdx.x;
    int total = (R + 1) * H * 64;
    if (i >= total) return;
    int d = i & 63;
    int hh = i >> 6;               // r*H + h
    int r = hh / H, h = hh % H;    // H compile-time -> shifts
    float v = (r < R) ? W[((size_t)r * 64 + d) * H + h]
                      : Wself[(size_t)d * H + h];
    Wt[i] = f2bf(v);
}

// ---------------------------------------------------------------------------
// MFMA relation GEMM: one 64-node tile per block, ALL relations inside the
// block (single A fetch). RT = compile-time R (8) -> r-loop fully unrolls:
// independent L2-resident B-fragment loads pipeline ahead of MFMAs; stores of
// iteration r overlap loads of r+1. 512 threads = 8 waves: wave = (node
// sub-tile w&3, column half w>>2). r==R -> self-loop, fp32+bias to Cself.
// ---------------------------------------------------------------------------
template<int H, int RT>   // H = 64/32; RT = 8 (unrolled) or 0 (runtime loop)
__global__ __launch_bounds__(512) void gemm_rel_mfma(
    const float* __restrict__ A, const unsigned short* __restrict__ Wt,
    const float* __restrict__ bias,
    unsigned short* __restrict__ C, float* __restrict__ Cself,
    int N, int Rrt, int relu)
{
    constexpr int AS = 72;   // 144 B/row = 36 words = 4 mod 32 -> 2-way (free)
    __shared__ unsigned short As[64 * AS];
    const int R = RT ? RT : Rrt;
    const int tid = threadIdx.x;
    const int n0 = blockIdx.x * 64;

    // Stage A tile fp32 -> bf16 (optional ReLU). 1024 float4 slots, 2 iters.
    #pragma unroll
    for (int i = 0; i < 2; ++i) {
        int lin = tid + i * 512;
        int n = lin >> 4;
        int d4 = (lin & 15) * 4;
        int gn = n0 + n;
        float4 v = make_float4(0.f, 0.f, 0.f, 0.f);
        if (gn < N) v = *(const float4*)&A[(size_t)gn * 64 + d4];
        if (relu) {
            v.x = fmaxf(v.x, 0.f); v.y = fmaxf(v.y, 0.f);
            v.z = fmaxf(v.z, 0.f); v.w = fmaxf(v.w, 0.f);
        }
        ushort4 u;
        u.x = f2bf(v.x); u.y = f2bf(v.y); u.z = f2bf(v.z); u.w = f2bf(v.w);
        *(ushort4*)&As[n * AS + d4] = u;
    }

    const int w = tid >> 6, lane = tid & 63;
    const int m = lane & 15, quad = lane >> 4;
    const int wt = w & 3;        // node sub-tile (16 nodes)
    const int half = w >> 2;     // column half (H/2 cols)

    __syncthreads();   // the only barrier

    short8 afrag[2];
    afrag[0] = *(const short8*)&As[(wt * 16 + m) * AS + 0 * 32 + quad * 8];
    afrag[1] = *(const short8*)&As[(wt * 16 + m) * AS + 1 * 32 + quad * 8];

    constexpr int NT = H / 32;   // col-tiles per wave (64->2, 32->1)
    #pragma unroll
    for (int r = 0; r <= R; ++r) {
        f32x4 acc[NT];
        #pragma unroll
        for (int nt = 0; nt < NT; ++nt) {
            const int colbase = half * (H / 2) + nt * 16;
            acc[nt] = (f32x4){0.f, 0.f, 0.f, 0.f};
            #pragma unroll
            for (int kc = 0; kc < 2; ++kc) {
                short8 bfrag = *(const short8*)
                    &Wt[((size_t)(r * H + colbase + m)) * 64 + kc * 32 + quad * 8];
                acc[nt] = __builtin_amdgcn_mfma_f32_16x16x32_bf16(afrag[kc], bfrag, acc[nt], 0, 0, 0);
            }
        }
        // C/D layout: col = colbase + (lane&15), row(node) = quad*4 + i.
        if (r < R) {
            #pragma unroll
            for (int nt = 0; nt < NT; ++nt) {
                int col = half * (H / 2) + nt * 16 + m;
                #pragma unroll
                for (int i = 0; i < 4; ++i) {
                    int node = n0 + wt * 16 + quad * 4 + i;
                    if (node < N)
                        C[((size_t)r * N + node) * H + col] = f2bf(acc[nt][i]);
                }
            }
        } else {
            #pragma unroll
            for (int nt = 0; nt < NT; ++nt) {
                int col = half * (H / 2) + nt * 16 + m;
                float bv = bias[col];
                #pragma unroll
                for (int i = 0; i < 4; ++i) {
                    int node = n0 + wt * 16 + quad * 4 + i;
                    if (node < N)
                        Cself[(size_t)node * H + col] = acc[nt][i] + bv;
                }
            }
        }
    }
}

// ---------------------------------------------------------------------------
// Bucket partition. Bucket = 64 consecutive dst nodes.
// Record: (et*N + src) << 6 | (dst & 63).
// ---------------------------------------------------------------------------
__global__ __launch_bounds__(256) void zero_int(int* __restrict__ p, int n) {
    int i = blockIdx.x * 256 + threadIdx.x;
    if (i < n) p[i] = 0;
}

__global__ __launch_bounds__(256) void fine_hist(
    const int* __restrict__ dst, int* __restrict__ ghist, int E, int B, int CH)
{
    __shared__ int hist[MAXB];
    const int t = threadIdx.x;
    const int e0 = blockIdx.x * CH, e1 = min(E, e0 + CH);
    for (int i = t; i < B; i += 256) hist[i] = 0;
    __syncthreads();
    for (int e = e0 + t; e < e1; e += 256) atomicAdd(&hist[dst[e] >> 6], 1);
    __syncthreads();
    for (int i = t; i < B; i += 256) {
        int h = hist[i];
        if (h) atomicAdd(&ghist[i], h);
    }
}

__global__ __launch_bounds__(256) void fine_scan(
    const int* __restrict__ ghist, int* __restrict__ bstart,
    int* __restrict__ cursor, int B, int E)
{
    __shared__ int ts[256];
    const int t = threadIdx.x;
    const int PER = (B + 255) / 256;   // <= 8
    int loc[8];
    int s = 0;
    for (int j = 0; j < PER; ++j) {
        int i = t * PER + j;
        loc[j] = (i < B) ? ghist[i] : 0;
        s += loc[j];
    }
    ts[t] = s;
    __syncthreads();
    for (int off = 1; off < 256; off <<= 1) {
        int x = (t >= off) ? ts[t - off] : 0;
        __syncthreads();
        ts[t] += x;
        __syncthreads();
    }
    int run = ts[t] - s;
    for (int j = 0; j < PER; ++j) {
        int i = t * PER + j;
        if (i < B) { bstart[i] = run; cursor[i] = run; }
        run += loc[j];
    }
    if (t == 255) bstart[B] = E;
}

__global__ __launch_bounds__(256) void partition_fine(
    const int* __restrict__ src, const int* __restrict__ dst,
    const int* __restrict__ et, int* __restrict__ cursor,
    int* __restrict__ rec, int E, int N, int B, int CH)
{
    __shared__ int hist[MAXB];
    __shared__ int base[MAXB];
    __shared__ int cnt[MAXB];
    const int t = threadIdx.x;
    const int e0 = blockIdx.x * CH, e1 = min(E, e0 + CH);

    for (int i = t; i < B; i += 256) hist[i] = 0;
    __syncthreads();
    for (int e = e0 + t; e < e1; e += 256) atomicAdd(&hist[dst[e] >> 6], 1);
    __syncthreads();
    for (int i = t; i < B; i += 256) {
        int h = hist[i];
        base[i] = h ? atomicAdd(&cursor[i], h) : 0;
        cnt[i] = 0;
    }
    __syncthreads();
    for (int e = e0 + t; e < e1; e += 256) {
        int d = dst[e];
        int b = d >> 6;
        int pos = base[b] + atomicAdd(&cnt[b], 1);
        rec[pos] = ((et[e] * N + src[e]) << 6) | (d & 63);
    }
}

// ---------------------------------------------------------------------------
// Per-bucket counting sort -> per-node CSR (row_ptr + eidx).
// ---------------------------------------------------------------------------
__global__ __launch_bounds__(256) void bucket_sort(
    const int* __restrict__ bstart, const int* __restrict__ rec,
    int* __restrict__ eidx, int* __restrict__ row_ptr, int N, int E)
{
    __shared__ int hist[64];
    __shared__ int excl[64];
    __shared__ int cur[64];
    const int b = blockIdx.x;
    const int tid = threadIdx.x;
    const int p0 = bstart[b], p1 = bstart[b + 1];

    if (tid < 64) hist[tid] = 0;
    __syncthreads();
    for (int p = p0 + tid; p < p1; p += 256)
        atomicAdd(&hist[rec[p] & 63], 1);
    __syncthreads();
    if (tid == 0) {
        int run = 0;
        #pragma unroll
        for (int i = 0; i < 64; ++i) { excl[i] = run; run += hist[i]; }
    }
    __syncthreads();
    if (tid < 64) {
        cur[tid] = excl[tid];
        int n = b * 64 + tid;
        if (n < N) row_ptr[n] = p0 + excl[tid];
    }
    if (b == 0 && tid == 0) row_ptr[N] = E;
    __syncthreads();
    for (int p = p0 + tid; p < p1; p += 256) {
        int rv = rec[p];
        int pos = p0 + atomicAdd(&cur[rv & 63], 1);
        eidx[pos] = rv >> 6;   // et*N + src
    }
}

// ---------------------------------------------------------------------------
// Gather-side aggregation over bf16 hW, fp32 register accumulate, 8-wide
// unroll with 4 accumulators for memory-level parallelism.
// ---------------------------------------------------------------------------
template<int F>
__global__ __launch_bounds__(256) void agg_csr(
    const unsigned short* __restrict__ hW, const int* __restrict__ row_ptr,
    const int* __restrict__ eidx, float* __restrict__ out, int N)
{
    constexpr int G = 256 / F;
    const int d = blockIdx.x * G + threadIdx.x / F;
    const int lane = threadIdx.x % F;
    if (d >= N) return;
    const int p1 = row_ptr[d + 1];
    int p = row_ptr[d];
    float a0 = 0.f, a1 = 0.f, a2 = 0.f, a3 = 0.f;
    for (; p + 7 < p1; p += 8) {
        int i0 = eidx[p],     i1 = eidx[p + 1], i2 = eidx[p + 2], i3 = eidx[p + 3];
        int i4 = eidx[p + 4], i5 = eidx[p + 5], i6 = eidx[p + 6], i7 = eidx[p + 7];
        a0 += bf2f(hW[(size_t)i0 * F + lane]);
        a1 += bf2f(hW[(size_t)i1 * F + lane]);
        a2 += bf2f(hW[(size_t)i2 * F + lane]);
        a3 += bf2f(hW[(size_t)i3 * F + lane]);
        a0 += bf2f(hW[(size_t)i4 * F + lane]);
        a1 += bf2f(hW[(size_t)i5 * F + lane]);
        a2 += bf2f(hW[(size_t)i6 * F + lane]);
        a3 += bf2f(hW[(size_t)i7 * F + lane]);
    }
    for (; p + 1 < p1; p += 2) {
        int i0 = eidx[p], i1 = eidx[p + 1];
        a0 += bf2f(hW[(size_t)i0 * F + lane]);
        a1 += bf2f(hW[(size_t)i1 * F + lane]);
    }
    if (p < p1) a0 += bf2f(hW[(size_t)eidx[p] * F + lane]);
    out[(size_t)d * F + lane] += (a0 + a1) + (a2 + a3);
}

extern "C" void kernel_launch(void* const* d_in, const int* in_sizes, int n_in,
                              void* d_out, int out_size, void* d_ws, size_t ws_size,
                              hipStream_t stream)
{
    const float* feat = (const float*)d_in[0];
    const int*   src  = (const int*)d_in[1];
    const int*   dst  = (const int*)d_in[2];
    const int*   et   = (const int*)d_in[3];
    const float* W1   = (const float*)d_in[4];
    const float* Ws1  = (const float*)d_in[5];
    const float* b1   = (const float*)d_in[6];
    const float* W2   = (const float*)d_in[7];
    const float* Ws2  = (const float*)d_in[8];
    const float* b2   = (const float*)d_in[9];
    float* out = (float*)d_out;

    const int N = in_sizes[0] / 64;           // 100000
    const int E = in_sizes[1];                // 1600000
    const int R = in_sizes[4] / (64 * 64);    // 8
    const int B = (N + 63) / 64;              // 1563 fine buckets

    // Workspace layout
    unsigned short* hW  = (unsigned short*)d_ws;           // [R][N][64] bf16 (reused [R][N][32])
    float* h1      = (float*)(hW + (size_t)R * N * 64);    // [N][64] fp32
    unsigned short* Wt1 = (unsigned short*)(h1 + (size_t)N * 64);  // [(R+1)*64*64]
    unsigned short* Wt2 = Wt1 + (size_t)(R + 1) * 64 * 64;         // [(R+1)*32*64]
    int*   ghist   = (int*)(Wt2 + (size_t)(R + 1) * 32 * 64);      // [B]
    int*   bstart  = ghist + B;                            // [B+1]
    int*   cursor  = bstart + (B + 1);                     // [B]
    int*   row_ptr = cursor + B;                           // [N+1]
    int*   rec     = row_ptr + (N + 1);                    // [E]
    int*   eidx    = rec + E;                              // [E]

    const dim3 blk(256);
    const int nblk64 = (N + 63) / 64;
    const int P  = 128;                       // partition blocks
    const int CH = (E + P - 1) / P;           // 12500 edges per block

    // ---- Weight pre-transpose (bf16, [r][h][d]) ----
    transpose_w<64><<<((R + 1) * 64 * 64 + 255) / 256, blk, 0, stream>>>(W1, Ws1, Wt1, R);
    transpose_w<32><<<((R + 1) * 32 * 64 + 255) / 256, blk, 0, stream>>>(W2, Ws2, Wt2, R);

    // ---- Build per-node CSR via bucket partition + per-bucket sort ----
    zero_int<<<(B + 255) / 256, blk, 0, stream>>>(ghist, B);
    fine_hist<<<P, blk, 0, stream>>>(dst, ghist, E, B, CH);
    fine_scan<<<1, blk, 0, stream>>>(ghist, bstart, cursor, B, E);
    partition_fine<<<P, blk, 0, stream>>>(src, dst, et, cursor, rec, E, N, B, CH);
    bucket_sort<<<B, blk, 0, stream>>>(bstart, rec, eidx, row_ptr, N, E);

    // ---- Layer 1 ---- (hW1 bf16 + self-loop fp32 into h1, fused)
    if (R == 8)
        gemm_rel_mfma<64, 8><<<nblk64, 512, 0, stream>>>(feat, Wt1, b1, hW, h1, N, R, 0);
    else
        gemm_rel_mfma<64, 0><<<nblk64, 512, 0, stream>>>(feat, Wt1, b1, hW, h1, N, R, 0);
    agg_csr<64><<<dim3((N + 3) / 4), blk, 0, stream>>>(hW, row_ptr, eidx, h1, N);

    // ---- Layer 2 ---- (ReLU fused into A staging)
    if (R == 8)
        gemm_rel_mfma<32, 8><<<nblk64, 512, 0, stream>>>(h1, Wt2, b2, hW, out, N, R, 1);
    else
        gemm_rel_mfma<32, 0><<<nblk64, 512, 0, stream>>>(h1, Wt2, b2, hW, out, N, R, 1);
    agg_csr<32><<<dim3((N + 7) / 8), blk, 0, stream>>>(hW, row_ptr, eidx, out, N);
}

// Round 10
// 394.173 us; speedup vs baseline: 1.1292x; 1.0120x over previous
//
#include <hip/hip_runtime.h>
#include <hip/hip_bf16.h>

typedef __attribute__((ext_vector_type(8))) short short8;
typedef __attribute__((ext_vector_type(4))) float f32x4;

__device__ __forceinline__ unsigned short f2bf(float v) {
    __hip_bfloat16 h = __float2bfloat16(v);   // RNE
    return *reinterpret_cast<unsigned short*>(&h);
}
__device__ __forceinline__ float bf2f(unsigned short u) {
    union { unsigned int i; float f; } x;
    x.i = (unsigned int)u << 16;
    return x.f;
}

constexpr int MAXB = 2048;   // max fine buckets (N/64 = 1563 here)

// ---------------------------------------------------------------------------
// Weight pre-transpose: Wt[(r*H + h)*64 + d] = bf16( r<R ? W[r][d][h]
//                                                        : Wself[d][h] ).
// ---------------------------------------------------------------------------
template<int H>
__global__ __launch_bounds__(256) void transpose_w(
    const float* __restrict__ W, const float* __restrict__ Wself,
    unsigned short* __restrict__ Wt, int R)
{
    int i = blockIdx.x * 256 + threadIdx.x;
    int total = (R + 1) * H * 64;
    if (i >= total) return;
    int d = i & 63;
    int hh = i >> 6;               // r*H + h
    int r = hh / H, h = hh % H;    // H compile-time -> shifts
    float v = (r < R) ? W[((size_t)r * 64 + d) * H + h]
                      : Wself[(size_t)d * H + h];
    Wt[i] = f2bf(v);
}

// ---------------------------------------------------------------------------
// MFMA relation GEMM: one 64-node tile per block, all relations inside
// (single A fetch). OPERANDS SWAPPED: D = W^T . feat^T = (feat.W)^T, so a
// lane's 4 acc regs are 4 CONSECUTIVE h-columns of one node -> one 8-B
// ushort4 store (r<R) or one float4 store (+float4 bias) for the self-loop.
// Depth-2 register prefetch of weight fragments (wf0/wf1/wn rotation) keeps
// the L2 loads for r+2 in flight while r computes.
// 512 threads = 8 waves: wave = (node sub-tile w&3, column half w>>2).
// ---------------------------------------------------------------------------
template<int H, int RT>   // H = 64/32; RT = 8 (unrolled) or 0 (runtime loop)
__global__ __launch_bounds__(512) void gemm_rel_mfma(
    const float* __restrict__ A, const unsigned short* __restrict__ Wt,
    const float* __restrict__ bias,
    unsigned short* __restrict__ C, float* __restrict__ Cself,
    int N, int Rrt, int relu)
{
    constexpr int AS = 72;   // 144 B/row = 36 words = 4 mod 32 -> 2-way (free)
    __shared__ unsigned short As[64 * AS];
    const int R = RT ? RT : Rrt;
    const int tid = threadIdx.x;
    const int n0 = blockIdx.x * 64;

    // Stage A tile fp32 -> bf16 (optional ReLU). 1024 float4 slots, 2 iters.
    #pragma unroll
    for (int i = 0; i < 2; ++i) {
        int lin = tid + i * 512;
        int n = lin >> 4;
        int d4 = (lin & 15) * 4;
        int gn = n0 + n;
        float4 v = make_float4(0.f, 0.f, 0.f, 0.f);
        if (gn < N) v = *(const float4*)&A[(size_t)gn * 64 + d4];
        if (relu) {
            v.x = fmaxf(v.x, 0.f); v.y = fmaxf(v.y, 0.f);
            v.z = fmaxf(v.z, 0.f); v.w = fmaxf(v.w, 0.f);
        }
        ushort4 u;
        u.x = f2bf(v.x); u.y = f2bf(v.y); u.z = f2bf(v.z); u.w = f2bf(v.w);
        *(ushort4*)&As[n * AS + d4] = u;
    }

    const int w = tid >> 6, lane = tid & 63;
    const int m = lane & 15, quad = lane >> 4;
    const int wt = w & 3;        // node sub-tile (16 nodes)
    const int half = w >> 2;     // column half (H/2 cols)
    const int node = n0 + wt * 16 + m;

    __syncthreads();   // the only barrier

    // Node fragment (used as B operand): B[k][n=lane&15] = feat[node][k].
    short8 afrag[2];
    afrag[0] = *(const short8*)&As[(wt * 16 + m) * AS + 0 * 32 + quad * 8];
    afrag[1] = *(const short8*)&As[(wt * 16 + m) * AS + 1 * 32 + quad * 8];

    constexpr int NT = H / 32;   // col-tiles per wave (64->2, 32->1)

    // Weight fragment address for (r, nt, kc): A-operand A[m=h][k=d].
    auto wptr = [&](int r, int nt, int kc) {
        int colbase = half * (H / 2) + nt * 16;
        return (const short8*)&Wt[((size_t)(r * H + colbase + m)) * 64 + kc * 32 + quad * 8];
    };

    short8 wf0[NT][2], wf1[NT][2];
    #pragma unroll
    for (int nt = 0; nt < NT; ++nt) { wf0[nt][0] = *wptr(0, nt, 0); wf0[nt][1] = *wptr(0, nt, 1); }
    #pragma unroll
    for (int nt = 0; nt < NT; ++nt) { wf1[nt][0] = *wptr(1, nt, 0); wf1[nt][1] = *wptr(1, nt, 1); }

    #pragma unroll
    for (int r = 0; r <= R; ++r) {
        // Prefetch r+2 while r computes.
        short8 wn[NT][2];
        if (r + 2 <= R) {
            #pragma unroll
            for (int nt = 0; nt < NT; ++nt) {
                wn[nt][0] = *wptr(r + 2, nt, 0);
                wn[nt][1] = *wptr(r + 2, nt, 1);
            }
        }

        f32x4 acc[NT];
        #pragma unroll
        for (int nt = 0; nt < NT; ++nt) {
            acc[nt] = (f32x4){0.f, 0.f, 0.f, 0.f};
            acc[nt] = __builtin_amdgcn_mfma_f32_16x16x32_bf16(wf0[nt][0], afrag[0], acc[nt], 0, 0, 0);
            acc[nt] = __builtin_amdgcn_mfma_f32_16x16x32_bf16(wf0[nt][1], afrag[1], acc[nt], 0, 0, 0);
        }

        // D layout (swapped): row = quad*4+i -> h, col = lane&15 -> node.
        if (r < R) {
            #pragma unroll
            for (int nt = 0; nt < NT; ++nt) {
                int colbase = half * (H / 2) + nt * 16;
                if (node < N) {
                    ushort4 u;
                    u.x = f2bf(acc[nt][0]); u.y = f2bf(acc[nt][1]);
                    u.z = f2bf(acc[nt][2]); u.w = f2bf(acc[nt][3]);
                    *(ushort4*)&C[((size_t)r * N + node) * H + colbase + quad * 4] = u;
                }
            }
        } else {
            #pragma unroll
            for (int nt = 0; nt < NT; ++nt) {
                int colbase = half * (H / 2) + nt * 16;
                if (node < N) {
                    float4 bv = *(const float4*)&bias[colbase + quad * 4];
                    float4 o = make_float4(acc[nt][0] + bv.x, acc[nt][1] + bv.y,
                                           acc[nt][2] + bv.z, acc[nt][3] + bv.w);
                    *(float4*)&Cself[(size_t)node * H + colbase + quad * 4] = o;
                }
            }
        }

        // Rotate prefetch buffers (register renaming, free under full unroll).
        #pragma unroll
        for (int nt = 0; nt < NT; ++nt) {
            wf0[nt][0] = wf1[nt][0]; wf0[nt][1] = wf1[nt][1];
            wf1[nt][0] = wn[nt][0];  wf1[nt][1] = wn[nt][1];
        }
    }
}

// ---------------------------------------------------------------------------
// Bucket partition. Bucket = 64 consecutive dst nodes.
// Record: (et*N + src) << 6 | (dst & 63).
// ---------------------------------------------------------------------------
__global__ __launch_bounds__(256) void zero_int(int* __restrict__ p, int n) {
    int i = blockIdx.x * 256 + threadIdx.x;
    if (i < n) p[i] = 0;
}

__global__ __launch_bounds__(256) void fine_hist(
    const int* __restrict__ dst, int* __restrict__ ghist, int E, int B, int CH)
{
    __shared__ int hist[MAXB];
    const int t = threadIdx.x;
    const int e0 = blockIdx.x * CH, e1 = min(E, e0 + CH);
    for (int i = t; i < B; i += 256) hist[i] = 0;
    __syncthreads();
    for (int e = e0 + t; e < e1; e += 256) atomicAdd(&hist[dst[e] >> 6], 1);
    __syncthreads();
    for (int i = t; i < B; i += 256) {
        int h = hist[i];
        if (h) atomicAdd(&ghist[i], h);
    }
}

__global__ __launch_bounds__(256) void fine_scan(
    const int* __restrict__ ghist, int* __restrict__ bstart,
    int* __restrict__ cursor, int B, int E)
{
    __shared__ int ts[256];
    const int t = threadIdx.x;
    const int PER = (B + 255) / 256;   // <= 8
    int loc[8];
    int s = 0;
    for (int j = 0; j < PER; ++j) {
        int i = t * PER + j;
        loc[j] = (i < B) ? ghist[i] : 0;
        s += loc[j];
    }
    ts[t] = s;
    __syncthreads();
    for (int off = 1; off < 256; off <<= 1) {
        int x = (t >= off) ? ts[t - off] : 0;
        __syncthreads();
        ts[t] += x;
        __syncthreads();
    }
    int run = ts[t] - s;
    for (int j = 0; j < PER; ++j) {
        int i = t * PER + j;
        if (i < B) { bstart[i] = run; cursor[i] = run; }
        run += loc[j];
    }
    if (t == 255) bstart[B] = E;
}

__global__ __launch_bounds__(256) void partition_fine(
    const int* __restrict__ src, const int* __restrict__ dst,
    const int* __restrict__ et, int* __restrict__ cursor,
    int* __restrict__ rec, int E, int N, int B, int CH)
{
    __shared__ int hist[MAXB];
    __shared__ int base[MAXB];
    __shared__ int cnt[MAXB];
    const int t = threadIdx.x;
    const int e0 = blockIdx.x * CH, e1 = min(E, e0 + CH);

    for (int i = t; i < B; i += 256) hist[i] = 0;
    __syncthreads();
    for (int e = e0 + t; e < e1; e += 256) atomicAdd(&hist[dst[e] >> 6], 1);
    __syncthreads();
    for (int i = t; i < B; i += 256) {
        int h = hist[i];
        base[i] = h ? atomicAdd(&cursor[i], h) : 0;
        cnt[i] = 0;
    }
    __syncthreads();
    for (int e = e0 + t; e < e1; e += 256) {
        int d = dst[e];
        int b = d >> 6;
        int pos = base[b] + atomicAdd(&cnt[b], 1);
        rec[pos] = ((et[e] * N + src[e]) << 6) | (d & 63);
    }
}

// ---------------------------------------------------------------------------
// Per-bucket counting sort -> per-node CSR (row_ptr + eidx).
// ---------------------------------------------------------------------------
__global__ __launch_bounds__(256) void bucket_sort(
    const int* __restrict__ bstart, const int* __restrict__ rec,
    int* __restrict__ eidx, int* __restrict__ row_ptr, int N, int E)
{
    __shared__ int hist[64];
    __shared__ int excl[64];
    __shared__ int cur[64];
    const int b = blockIdx.x;
    const int tid = threadIdx.x;
    const int p0 = bstart[b], p1 = bstart[b + 1];

    if (tid < 64) hist[tid] = 0;
    __syncthreads();
    for (int p = p0 + tid; p < p1; p += 256)
        atomicAdd(&hist[rec[p] & 63], 1);
    __syncthreads();
    if (tid == 0) {
        int run = 0;
        #pragma unroll
        for (int i = 0; i < 64; ++i) { excl[i] = run; run += hist[i]; }
    }
    __syncthreads();
    if (tid < 64) {
        cur[tid] = excl[tid];
        int n = b * 64 + tid;
        if (n < N) row_ptr[n] = p0 + excl[tid];
    }
    if (b == 0 && tid == 0) row_ptr[N] = E;
    __syncthreads();
    for (int p = p0 + tid; p < p1; p += 256) {
        int rv = rec[p];
        int pos = p0 + atomicAdd(&cur[rv & 63], 1);
        eidx[pos] = rv >> 6;   // et*N + src
    }
}

// ---------------------------------------------------------------------------
// Gather-side aggregation over bf16 hW, fp32 register accumulate, 8-wide
// unroll with 4 accumulators for memory-level parallelism.
// ---------------------------------------------------------------------------
template<int F>
__global__ __launch_bounds__(256) void agg_csr(
    const unsigned short* __restrict__ hW, const int* __restrict__ row_ptr,
    const int* __restrict__ eidx, float* __restrict__ out, int N)
{
    constexpr int G = 256 / F;
    const int d = blockIdx.x * G + threadIdx.x / F;
    const int lane = threadIdx.x % F;
    if (d >= N) return;
    const int p1 = row_ptr[d + 1];
    int p = row_ptr[d];
    float a0 = 0.f, a1 = 0.f, a2 = 0.f, a3 = 0.f;
    for (; p + 7 < p1; p += 8) {
        int i0 = eidx[p],     i1 = eidx[p + 1], i2 = eidx[p + 2], i3 = eidx[p + 3];
        int i4 = eidx[p + 4], i5 = eidx[p + 5], i6 = eidx[p + 6], i7 = eidx[p + 7];
        a0 += bf2f(hW[(size_t)i0 * F + lane]);
        a1 += bf2f(hW[(size_t)i1 * F + lane]);
        a2 += bf2f(hW[(size_t)i2 * F + lane]);
        a3 += bf2f(hW[(size_t)i3 * F + lane]);
        a0 += bf2f(hW[(size_t)i4 * F + lane]);
        a1 += bf2f(hW[(size_t)i5 * F + lane]);
        a2 += bf2f(hW[(size_t)i6 * F + lane]);
        a3 += bf2f(hW[(size_t)i7 * F + lane]);
    }
    for (; p + 1 < p1; p += 2) {
        int i0 = eidx[p], i1 = eidx[p + 1];
        a0 += bf2f(hW[(size_t)i0 * F + lane]);
        a1 += bf2f(hW[(size_t)i1 * F + lane]);
    }
    if (p < p1) a0 += bf2f(hW[(size_t)eidx[p] * F + lane]);
    out[(size_t)d * F + lane] += (a0 + a1) + (a2 + a3);
}

extern "C" void kernel_launch(void* const* d_in, const int* in_sizes, int n_in,
                              void* d_out, int out_size, void* d_ws, size_t ws_size,
                              hipStream_t stream)
{
    const float* feat = (const float*)d_in[0];
    const int*   src  = (const int*)d_in[1];
    const int*   dst  = (const int*)d_in[2];
    const int*   et   = (const int*)d_in[3];
    const float* W1   = (const float*)d_in[4];
    const float* Ws1  = (const float*)d_in[5];
    const float* b1   = (const float*)d_in[6];
    const float* W2   = (const float*)d_in[7];
    const float* Ws2  = (const float*)d_in[8];
    const float* b2   = (const float*)d_in[9];
    float* out = (float*)d_out;

    const int N = in_sizes[0] / 64;           // 100000
    const int E = in_sizes[1];                // 1600000
    const int R = in_sizes[4] / (64 * 64);    // 8
    const int B = (N + 63) / 64;              // 1563 fine buckets

    // Workspace layout
    unsigned short* hW  = (unsigned short*)d_ws;           // [R][N][64] bf16 (reused [R][N][32])
    float* h1      = (float*)(hW + (size_t)R * N * 64);    // [N][64] fp32
    unsigned short* Wt1 = (unsigned short*)(h1 + (size_t)N * 64);  // [(R+1)*64*64]
    unsigned short* Wt2 = Wt1 + (size_t)(R + 1) * 64 * 64;         // [(R+1)*32*64]
    int*   ghist   = (int*)(Wt2 + (size_t)(R + 1) * 32 * 64);      // [B]
    int*   bstart  = ghist + B;                            // [B+1]
    int*   cursor  = bstart + (B + 1);                     // [B]
    int*   row_ptr = cursor + B;                           // [N+1]
    int*   rec     = row_ptr + (N + 1);                    // [E]
    int*   eidx    = rec + E;                              // [E]

    const dim3 blk(256);
    const int nblk64 = (N + 63) / 64;
    const int P  = 128;                       // partition blocks
    const int CH = (E + P - 1) / P;           // 12500 edges per block

    // ---- Weight pre-transpose (bf16, [r][h][d]) ----
    transpose_w<64><<<((R + 1) * 64 * 64 + 255) / 256, blk, 0, stream>>>(W1, Ws1, Wt1, R);
    transpose_w<32><<<((R + 1) * 32 * 64 + 255) / 256, blk, 0, stream>>>(W2, Ws2, Wt2, R);

    // ---- Build per-node CSR via bucket partition + per-bucket sort ----
    zero_int<<<(B + 255) / 256, blk, 0, stream>>>(ghist, B);
    fine_hist<<<P, blk, 0, stream>>>(dst, ghist, E, B, CH);
    fine_scan<<<1, blk, 0, stream>>>(ghist, bstart, cursor, B, E);
    partition_fine<<<P, blk, 0, stream>>>(src, dst, et, cursor, rec, E, N, B, CH);
    bucket_sort<<<B, blk, 0, stream>>>(bstart, rec, eidx, row_ptr, N, E);

    // ---- Layer 1 ---- (hW1 bf16 + self-loop fp32 into h1, fused)
    if (R == 8)
        gemm_rel_mfma<64, 8><<<nblk64, 512, 0, stream>>>(feat, Wt1, b1, hW, h1, N, R, 0);
    else
        gemm_rel_mfma<64, 0><<<nblk64, 512, 0, stream>>>(feat, Wt1, b1, hW, h1, N, R, 0);
    agg_csr<64><<<dim3((N + 3) / 4), blk, 0, stream>>>(hW, row_ptr, eidx, h1, N);

    // ---- Layer 2 ---- (ReLU fused into A staging)
    if (R == 8)
        gemm_rel_mfma<32, 8><<<nblk64, 512, 0, stream>>>(h1, Wt2, b2, hW, out, N, R, 1);
    else
        gemm_rel_mfma<32, 0><<<nblk64, 512, 0, stream>>>(h1, Wt2, b2, hW, out, N, R, 1);
    agg_csr<32><<<dim3((N + 7) / 8), blk, 0, stream>>>(hW, row_ptr, eidx, out, N);
}

// Round 11
// 375.534 us; speedup vs baseline: 1.1853x; 1.0496x over previous
//
#include <hip/hip_runtime.h>
#include <hip/hip_bf16.h>

typedef __attribute__((ext_vector_type(8))) short short8;
typedef __attribute__((ext_vector_type(4))) float f32x4;

__device__ __forceinline__ unsigned short f2bf(float v) {
    __hip_bfloat16 h = __float2bfloat16(v);   // RNE
    return *reinterpret_cast<unsigned short*>(&h);
}
__device__ __forceinline__ float bf2f(unsigned short u) {
    union { unsigned int i; float f; } x;
    x.i = (unsigned int)u << 16;
    return x.f;
}

constexpr int MAXB = 2048;   // max fine buckets (N/64 = 1563 here)

// ---------------------------------------------------------------------------
// Weight pre-transpose: Wt[(r*H + h)*64 + d] = bf16( r<R ? W[r][d][h]
//                                                        : Wself[d][h] ).
// ---------------------------------------------------------------------------
template<int H>
__global__ __launch_bounds__(256) void transpose_w(
    const float* __restrict__ W, const float* __restrict__ Wself,
    unsigned short* __restrict__ Wt, int R)
{
    int i = blockIdx.x * 256 + threadIdx.x;
    int total = (R + 1) * H * 64;
    if (i >= total) return;
    int d = i & 63;
    int hh = i >> 6;               // r*H + h
    int r = hh / H, h = hh % H;    // H compile-time -> shifts
    float v = (r < R) ? W[((size_t)r * 64 + d) * H + h]
                      : Wself[(size_t)d * H + h];
    Wt[i] = f2bf(v);
}

// ---------------------------------------------------------------------------
// MFMA relation GEMM (R10 structure: operand-swapped, depth-2 W prefetch).
// ABF: A input is bf16 (layer2, h1) vs fp32 (layer1, feat).
// SBF: self-loop output is bf16 (layer1 -> h1) vs fp32 (layer2 -> out).
// ---------------------------------------------------------------------------
template<int H, int RT, bool ABF, bool SBF>
__global__ __launch_bounds__(512) void gemm_rel_mfma(
    const void* __restrict__ Av, const unsigned short* __restrict__ Wt,
    const float* __restrict__ bias,
    unsigned short* __restrict__ C, void* __restrict__ Cselfv,
    int N, int Rrt, int relu)
{
    constexpr int AS = 72;   // 144 B/row = 36 words = 4 mod 32 -> 2-way (free)
    __shared__ unsigned short As[64 * AS];
    const int R = RT ? RT : Rrt;
    const int tid = threadIdx.x;
    const int n0 = blockIdx.x * 64;

    if constexpr (ABF) {
        // bf16 input: 64x64 = 4096 ushorts = exactly 512 short8 slots.
        const unsigned short* A = (const unsigned short*)Av;
        int n = tid >> 3, d8 = (tid & 7) * 8;
        int gn = n0 + n;
        short8 u = {};
        if (gn < N) u = *(const short8*)&A[(size_t)gn * 64 + d8];
        if (relu) {
            #pragma unroll
            for (int j = 0; j < 8; ++j) {
                unsigned short x = (unsigned short)u[j];
                u[j] = (short)((x & 0x8000) ? 0 : x);   // bf16 relu = sign test
            }
        }
        *(short8*)&As[n * AS + d8] = u;
    } else {
        const float* A = (const float*)Av;
        #pragma unroll
        for (int i = 0; i < 2; ++i) {
            int lin = tid + i * 512;
            int n = lin >> 4;
            int d4 = (lin & 15) * 4;
            int gn = n0 + n;
            float4 v = make_float4(0.f, 0.f, 0.f, 0.f);
            if (gn < N) v = *(const float4*)&A[(size_t)gn * 64 + d4];
            if (relu) {
                v.x = fmaxf(v.x, 0.f); v.y = fmaxf(v.y, 0.f);
                v.z = fmaxf(v.z, 0.f); v.w = fmaxf(v.w, 0.f);
            }
            ushort4 u;
            u.x = f2bf(v.x); u.y = f2bf(v.y); u.z = f2bf(v.z); u.w = f2bf(v.w);
            *(ushort4*)&As[n * AS + d4] = u;
        }
    }

    const int w = tid >> 6, lane = tid & 63;
    const int m = lane & 15, quad = lane >> 4;
    const int wt = w & 3;        // node sub-tile (16 nodes)
    const int half = w >> 2;     // column half (H/2 cols)
    const int node = n0 + wt * 16 + m;

    __syncthreads();   // the only barrier

    // Node fragment (B operand): B[k][n=lane&15] = feat[node][k].
    short8 afrag[2];
    afrag[0] = *(const short8*)&As[(wt * 16 + m) * AS + 0 * 32 + quad * 8];
    afrag[1] = *(const short8*)&As[(wt * 16 + m) * AS + 1 * 32 + quad * 8];

    constexpr int NT = H / 32;   // col-tiles per wave (64->2, 32->1)

    auto wptr = [&](int r, int nt, int kc) {
        int colbase = half * (H / 2) + nt * 16;
        return (const short8*)&Wt[((size_t)(r * H + colbase + m)) * 64 + kc * 32 + quad * 8];
    };

    short8 wf0[NT][2], wf1[NT][2];
    #pragma unroll
    for (int nt = 0; nt < NT; ++nt) { wf0[nt][0] = *wptr(0, nt, 0); wf0[nt][1] = *wptr(0, nt, 1); }
    #pragma unroll
    for (int nt = 0; nt < NT; ++nt) { wf1[nt][0] = *wptr(1, nt, 0); wf1[nt][1] = *wptr(1, nt, 1); }

    #pragma unroll
    for (int r = 0; r <= R; ++r) {
        short8 wn[NT][2];
        if (r + 2 <= R) {
            #pragma unroll
            for (int nt = 0; nt < NT; ++nt) {
                wn[nt][0] = *wptr(r + 2, nt, 0);
                wn[nt][1] = *wptr(r + 2, nt, 1);
            }
        }

        f32x4 acc[NT];
        #pragma unroll
        for (int nt = 0; nt < NT; ++nt) {
            acc[nt] = (f32x4){0.f, 0.f, 0.f, 0.f};
            acc[nt] = __builtin_amdgcn_mfma_f32_16x16x32_bf16(wf0[nt][0], afrag[0], acc[nt], 0, 0, 0);
            acc[nt] = __builtin_amdgcn_mfma_f32_16x16x32_bf16(wf0[nt][1], afrag[1], acc[nt], 0, 0, 0);
        }

        // D layout (swapped): row = quad*4+i -> h-col, col = lane&15 -> node.
        if (r < R) {
            #pragma unroll
            for (int nt = 0; nt < NT; ++nt) {
                int colbase = half * (H / 2) + nt * 16;
                if (node < N) {
                    ushort4 u;
                    u.x = f2bf(acc[nt][0]); u.y = f2bf(acc[nt][1]);
                    u.z = f2bf(acc[nt][2]); u.w = f2bf(acc[nt][3]);
                    *(ushort4*)&C[((size_t)r * N + node) * H + colbase + quad * 4] = u;
                }
            }
        } else {
            #pragma unroll
            for (int nt = 0; nt < NT; ++nt) {
                int colbase = half * (H / 2) + nt * 16;
                if (node < N) {
                    float4 bv = *(const float4*)&bias[colbase + quad * 4];
                    if constexpr (SBF) {
                        unsigned short* Cs = (unsigned short*)Cselfv;
                        ushort4 u;
                        u.x = f2bf(acc[nt][0] + bv.x); u.y = f2bf(acc[nt][1] + bv.y);
                        u.z = f2bf(acc[nt][2] + bv.z); u.w = f2bf(acc[nt][3] + bv.w);
                        *(ushort4*)&Cs[(size_t)node * H + colbase + quad * 4] = u;
                    } else {
                        float* Cs = (float*)Cselfv;
                        float4 o = make_float4(acc[nt][0] + bv.x, acc[nt][1] + bv.y,
                                               acc[nt][2] + bv.z, acc[nt][3] + bv.w);
                        *(float4*)&Cs[(size_t)node * H + colbase + quad * 4] = o;
                    }
                }
            }
        }

        #pragma unroll
        for (int nt = 0; nt < NT; ++nt) {
            wf0[nt][0] = wf1[nt][0]; wf0[nt][1] = wf1[nt][1];
            wf1[nt][0] = wn[nt][0];  wf1[nt][1] = wn[nt][1];
        }
    }
}

// ---------------------------------------------------------------------------
// Bucket partition. Bucket = 64 consecutive dst nodes.
// Record: (et*N + src) << 6 | (dst & 63).
// ---------------------------------------------------------------------------
__global__ __launch_bounds__(256) void zero_int(int* __restrict__ p, int n) {
    int i = blockIdx.x * 256 + threadIdx.x;
    if (i < n) p[i] = 0;
}

__global__ __launch_bounds__(256) void fine_hist(
    const int* __restrict__ dst, int* __restrict__ ghist, int E, int B, int CH)
{
    __shared__ int hist[MAXB];
    const int t = threadIdx.x;
    const int e0 = blockIdx.x * CH, e1 = min(E, e0 + CH);
    for (int i = t; i < B; i += 256) hist[i] = 0;
    __syncthreads();
    for (int e = e0 + t; e < e1; e += 256) atomicAdd(&hist[dst[e] >> 6], 1);
    __syncthreads();
    for (int i = t; i < B; i += 256) {
        int h = hist[i];
        if (h) atomicAdd(&ghist[i], h);
    }
}

__global__ __launch_bounds__(256) void fine_scan(
    const int* __restrict__ ghist, int* __restrict__ bstart,
    int* __restrict__ cursor, int B, int E)
{
    __shared__ int ts[256];
    const int t = threadIdx.x;
    const int PER = (B + 255) / 256;   // <= 8
    int loc[8];
    int s = 0;
    for (int j = 0; j < PER; ++j) {
        int i = t * PER + j;
        loc[j] = (i < B) ? ghist[i] : 0;
        s += loc[j];
    }
    ts[t] = s;
    __syncthreads();
    for (int off = 1; off < 256; off <<= 1) {
        int x = (t >= off) ? ts[t - off] : 0;
        __syncthreads();
        ts[t] += x;
        __syncthreads();
    }
    int run = ts[t] - s;
    for (int j = 0; j < PER; ++j) {
        int i = t * PER + j;
        if (i < B) { bstart[i] = run; cursor[i] = run; }
        run += loc[j];
    }
    if (t == 255) bstart[B] = E;
}

__global__ __launch_bounds__(256) void partition_fine(
    const int* __restrict__ src, const int* __restrict__ dst,
    const int* __restrict__ et, int* __restrict__ cursor,
    int* __restrict__ rec, int E, int N, int B, int CH)
{
    __shared__ int hist[MAXB];
    __shared__ int base[MAXB];
    __shared__ int cnt[MAXB];
    const int t = threadIdx.x;
    const int e0 = blockIdx.x * CH, e1 = min(E, e0 + CH);

    for (int i = t; i < B; i += 256) hist[i] = 0;
    __syncthreads();
    for (int e = e0 + t; e < e1; e += 256) atomicAdd(&hist[dst[e] >> 6], 1);
    __syncthreads();
    for (int i = t; i < B; i += 256) {
        int h = hist[i];
        base[i] = h ? atomicAdd(&cursor[i], h) : 0;
        cnt[i] = 0;
    }
    __syncthreads();
    for (int e = e0 + t; e < e1; e += 256) {
        int d = dst[e];
        int b = d >> 6;
        int pos = base[b] + atomicAdd(&cnt[b], 1);
        rec[pos] = ((et[e] * N + src[e]) << 6) | (d & 63);
    }
}

// ---------------------------------------------------------------------------
// Per-bucket counting sort -> per-node CSR (row_ptr + eidx).
// ---------------------------------------------------------------------------
__global__ __launch_bounds__(256) void bucket_sort(
    const int* __restrict__ bstart, const int* __restrict__ rec,
    int* __restrict__ eidx, int* __restrict__ row_ptr, int N, int E)
{
    __shared__ int hist[64];
    __shared__ int excl[64];
    __shared__ int cur[64];
    const int b = blockIdx.x;
    const int tid = threadIdx.x;
    const int p0 = bstart[b], p1 = bstart[b + 1];

    if (tid < 64) hist[tid] = 0;
    __syncthreads();
    for (int p = p0 + tid; p < p1; p += 256)
        atomicAdd(&hist[rec[p] & 63], 1);
    __syncthreads();
    if (tid == 0) {
        int run = 0;
        #pragma unroll
        for (int i = 0; i < 64; ++i) { excl[i] = run; run += hist[i]; }
    }
    __syncthreads();
    if (tid < 64) {
        cur[tid] = excl[tid];
        int n = b * 64 + tid;
        if (n < N) row_ptr[n] = p0 + excl[tid];
    }
    if (b == 0 && tid == 0) row_ptr[N] = E;
    __syncthreads();
    for (int p = p0 + tid; p < p1; p += 256) {
        int rv = rec[p];
        int pos = p0 + atomicAdd(&cur[rv & 63], 1);
        eidx[pos] = rv >> 6;   // et*N + src
    }
}

// ---------------------------------------------------------------------------
// agg64: one 64-lane wave per dst node. Lane loads a packed uint (2 bf16
// cols); the two 32-lane halves walk alternate edges (2-edge MLP + 4-deep
// unroll = 8 in flight). Combine via shfl; h1 is bf16 (packed uint I/O).
// ---------------------------------------------------------------------------
__global__ __launch_bounds__(256) void agg_csr64(
    const unsigned int* __restrict__ hw32, const int* __restrict__ row_ptr,
    const int* __restrict__ eidx, unsigned int* __restrict__ out32, int N)
{
    const int d = blockIdx.x * 4 + (threadIdx.x >> 6);
    const int lane = threadIdx.x & 63;
    if (d >= N) return;
    const int he = lane >> 5;     // which edge of each pair
    const int c = lane & 31;      // uint col (2 bf16 cols)
    const int p0 = row_ptr[d], p1 = row_ptr[d + 1];
    float s0 = 0.f, s1 = 0.f, t0 = 0.f, t1 = 0.f;
    int p = p0 + he;
    for (; p + 6 < p1; p += 8) {
        unsigned int v0 = hw32[(size_t)eidx[p]     * 32 + c];
        unsigned int v1 = hw32[(size_t)eidx[p + 2] * 32 + c];
        unsigned int v2 = hw32[(size_t)eidx[p + 4] * 32 + c];
        unsigned int v3 = hw32[(size_t)eidx[p + 6] * 32 + c];
        s0 += bf2f((unsigned short)(v0 & 0xffff)); s1 += bf2f((unsigned short)(v0 >> 16));
        t0 += bf2f((unsigned short)(v1 & 0xffff)); t1 += bf2f((unsigned short)(v1 >> 16));
        s0 += bf2f((unsigned short)(v2 & 0xffff)); s1 += bf2f((unsigned short)(v2 >> 16));
        t0 += bf2f((unsigned short)(v3 & 0xffff)); t1 += bf2f((unsigned short)(v3 >> 16));
    }
    for (; p < p1; p += 2) {
        unsigned int v = hw32[(size_t)eidx[p] * 32 + c];
        s0 += bf2f((unsigned short)(v & 0xffff)); s1 += bf2f((unsigned short)(v >> 16));
    }
    s0 += t0; s1 += t1;
    float u0 = __shfl(s0, c + 32, 64);   // partner in upper half
    float u1 = __shfl(s1, c + 32, 64);
    if (he == 0) {
        unsigned int cur = out32[(size_t)d * 32 + c];
        float o0 = s0 + u0 + bf2f((unsigned short)(cur & 0xffff));
        float o1 = s1 + u1 + bf2f((unsigned short)(cur >> 16));
        out32[(size_t)d * 32 + c] = (unsigned int)f2bf(o0) | ((unsigned int)f2bf(o1) << 16);
    }
}

// ---------------------------------------------------------------------------
// agg32: 32 lanes per dst node (8 nodes/block); 16-lane halves walk alternate
// edges with packed-uint loads; combine via shfl; out is fp32 (d_out).
// ---------------------------------------------------------------------------
__global__ __launch_bounds__(256) void agg_csr32(
    const unsigned int* __restrict__ hw32, const int* __restrict__ row_ptr,
    const int* __restrict__ eidx, float* __restrict__ out, int N)
{
    const int d = blockIdx.x * 8 + (threadIdx.x >> 5);
    const int l = threadIdx.x & 31;
    if (d >= N) return;
    const int he = l >> 4;
    const int c = l & 15;         // uint col (2 bf16 cols of 32)
    const int p0 = row_ptr[d], p1 = row_ptr[d + 1];
    float s0 = 0.f, s1 = 0.f, t0 = 0.f, t1 = 0.f;
    int p = p0 + he;
    for (; p + 6 < p1; p += 8) {
        unsigned int v0 = hw32[(size_t)eidx[p]     * 16 + c];
        unsigned int v1 = hw32[(size_t)eidx[p + 2] * 16 + c];
        unsigned int v2 = hw32[(size_t)eidx[p + 4] * 16 + c];
        unsigned int v3 = hw32[(size_t)eidx[p + 6] * 16 + c];
        s0 += bf2f((unsigned short)(v0 & 0xffff)); s1 += bf2f((unsigned short)(v0 >> 16));
        t0 += bf2f((unsigned short)(v1 & 0xffff)); t1 += bf2f((unsigned short)(v1 >> 16));
        s0 += bf2f((unsigned short)(v2 & 0xffff)); s1 += bf2f((unsigned short)(v2 >> 16));
        t0 += bf2f((unsigned short)(v3 & 0xffff)); t1 += bf2f((unsigned short)(v3 >> 16));
    }
    for (; p < p1; p += 2) {
        unsigned int v = hw32[(size_t)eidx[p] * 16 + c];
        s0 += bf2f((unsigned short)(v & 0xffff)); s1 += bf2f((unsigned short)(v >> 16));
    }
    s0 += t0; s1 += t1;
    float u0 = __shfl(s0, (threadIdx.x & 63) ^ 16, 64);
    float u1 = __shfl(s1, (threadIdx.x & 63) ^ 16, 64);
    if (he == 0) {
        float2 cur = *(const float2*)&out[(size_t)d * 32 + c * 2];
        float2 o = make_float2(cur.x + s0 + u0, cur.y + s1 + u1);
        *(float2*)&out[(size_t)d * 32 + c * 2] = o;
    }
}

extern "C" void kernel_launch(void* const* d_in, const int* in_sizes, int n_in,
                              void* d_out, int out_size, void* d_ws, size_t ws_size,
                              hipStream_t stream)
{
    const float* feat = (const float*)d_in[0];
    const int*   src  = (const int*)d_in[1];
    const int*   dst  = (const int*)d_in[2];
    const int*   et   = (const int*)d_in[3];
    const float* W1   = (const float*)d_in[4];
    const float* Ws1  = (const float*)d_in[5];
    const float* b1   = (const float*)d_in[6];
    const float* W2   = (const float*)d_in[7];
    const float* Ws2  = (const float*)d_in[8];
    const float* b2   = (const float*)d_in[9];
    float* out = (float*)d_out;

    const int N = in_sizes[0] / 64;           // 100000
    const int E = in_sizes[1];                // 1600000
    const int R = in_sizes[4] / (64 * 64);    // 8
    const int B = (N + 63) / 64;              // 1563 fine buckets

    // Workspace layout
    unsigned short* hW  = (unsigned short*)d_ws;           // [R][N][64] bf16 (reused [R][N][32])
    unsigned short* h1  = hW + (size_t)R * N * 64;         // [N][64] bf16
    unsigned short* Wt1 = h1 + (size_t)N * 64;             // [(R+1)*64*64]
    unsigned short* Wt2 = Wt1 + (size_t)(R + 1) * 64 * 64; // [(R+1)*32*64]
    int*   ghist   = (int*)(Wt2 + (size_t)(R + 1) * 32 * 64);  // [B]
    int*   bstart  = ghist + B;                            // [B+1]
    int*   cursor  = bstart + (B + 1);                     // [B]
    int*   row_ptr = cursor + B;                           // [N+1]
    int*   rec     = row_ptr + (N + 1);                    // [E]
    int*   eidx    = rec + E;                              // [E]

    const dim3 blk(256);
    const int nblk64 = (N + 63) / 64;
    const int P  = 128;                       // partition blocks
    const int CH = (E + P - 1) / P;           // 12500 edges per block

    // ---- Weight pre-transpose (bf16, [r][h][d]) ----
    transpose_w<64><<<((R + 1) * 64 * 64 + 255) / 256, blk, 0, stream>>>(W1, Ws1, Wt1, R);
    transpose_w<32><<<((R + 1) * 32 * 64 + 255) / 256, blk, 0, stream>>>(W2, Ws2, Wt2, R);

    // ---- Build per-node CSR via bucket partition + per-bucket sort ----
    zero_int<<<(B + 255) / 256, blk, 0, stream>>>(ghist, B);
    fine_hist<<<P, blk, 0, stream>>>(dst, ghist, E, B, CH);
    fine_scan<<<1, blk, 0, stream>>>(ghist, bstart, cursor, B, E);
    partition_fine<<<P, blk, 0, stream>>>(src, dst, et, cursor, rec, E, N, B, CH);
    bucket_sort<<<B, blk, 0, stream>>>(bstart, rec, eidx, row_ptr, N, E);

    // ---- Layer 1 ---- (hW1 bf16 + self-loop bf16 into h1, fused)
    if (R == 8)
        gemm_rel_mfma<64, 8, false, true><<<nblk64, 512, 0, stream>>>(feat, Wt1, b1, hW, h1, N, R, 0);
    else
        gemm_rel_mfma<64, 0, false, true><<<nblk64, 512, 0, stream>>>(feat, Wt1, b1, hW, h1, N, R, 0);
    agg_csr64<<<dim3((N + 3) / 4), blk, 0, stream>>>((const unsigned int*)hW, row_ptr, eidx,
                                                     (unsigned int*)h1, N);

    // ---- Layer 2 ---- (bf16 A staging with bit-mask ReLU; self fp32 -> out)
    if (R == 8)
        gemm_rel_mfma<32, 8, true, false><<<nblk64, 512, 0, stream>>>(h1, Wt2, b2, hW, out, N, R, 1);
    else
        gemm_rel_mfma<32, 0, true, false><<<nblk64, 512, 0, stream>>>(h1, Wt2, b2, hW, out, N, R, 1);
    agg_csr32<<<dim3((N + 7) / 8), blk, 0, stream>>>((const unsigned int*)hW, row_ptr, eidx, out, N);
}